// Round 1
// baseline (1372.381 us; speedup 1.0000x reference)
//
#include <hip/hip_runtime.h>

#define NM 100000
#define NB 200000
#define NG 5000
#define NE1 400000
#define NE2 100000
#define NE (NE1 + NE2)

// ---------------------------------------------------------------------------
// MLP: x(64) -> ELU(xW0+b0) -> ELU(hW1+b1) -> hW2 (256), per row.
// Block = 256 threads = 4 waves; wave w handles row r0+w entirely.
// Also computes score[row][h] = sum_d ft[h][d]*attn[h][d] (er or el).
// ft_out may be nullptr (master nodes: ft never needed downstream).
// ---------------------------------------------------------------------------
__global__ __launch_bounds__(256) void mlp_kernel(
    const float* __restrict__ x,
    const float* __restrict__ W0, const float* __restrict__ b0,
    const float* __restrict__ W1, const float* __restrict__ b1,
    const float* __restrict__ W2,
    const float* __restrict__ attn,   // (4,64)
    float* __restrict__ score,        // (N,4)
    float* __restrict__ ft_out)       // (N,256) or nullptr
{
    __shared__ float xs[256];
    __shared__ float h0s[256];
    __shared__ float h1s[256];
    const int tid  = threadIdx.x;
    const int w    = tid >> 6;
    const int lane = tid & 63;
    const int r0   = blockIdx.x << 2;

    // stage 4 input rows (coalesced)
    xs[tid] = x[(r0 << 6) + tid];
    __syncthreads();

    // layer 1: lane computes h0[lane] for row r0+w
    float acc1 = b0[lane];
    {
        const float* xr = &xs[w << 6];
        #pragma unroll 8
        for (int k = 0; k < 64; ++k)
            acc1 = fmaf(xr[k], W0[(k << 6) + lane], acc1);
    }
    h0s[(w << 6) + lane] = acc1 > 0.f ? acc1 : expm1f(acc1);  // ELU
    __syncthreads();

    // layer 2
    float acc2 = b1[lane];
    {
        const float* hr = &h0s[w << 6];
        #pragma unroll 8
        for (int k = 0; k < 64; ++k)
            acc2 = fmaf(hr[k], W1[(k << 6) + lane], acc2);
    }
    h1s[(w << 6) + lane] = acc2 > 0.f ? acc2 : expm1f(acc2);  // ELU
    __syncthreads();

    // layer 3: lane computes outputs o = lane*4 .. lane*4+3 (float4 W2 loads)
    float4 a = make_float4(0.f, 0.f, 0.f, 0.f);
    {
        const float*  hr  = &h1s[w << 6];
        const float4* W2v = (const float4*)W2;   // W2[k][o], o block of 4 = lane
        #pragma unroll 8
        for (int k = 0; k < 64; ++k) {
            const float  hv = hr[k];
            const float4 wv = W2v[(k << 6) + lane];
            a.x = fmaf(hv, wv.x, a.x);
            a.y = fmaf(hv, wv.y, a.y);
            a.z = fmaf(hv, wv.z, a.z);
            a.w = fmaf(hv, wv.w, a.w);
        }
    }
    const int row = r0 + w;
    if (ft_out) {
        *(float4*)&ft_out[((size_t)row << 8) + (lane << 2)] = a;
    }

    // score: o = lane*4+q -> h = lane>>4, d = (lane&15)*4+q
    const int h = lane >> 4;
    const float4 av = ((const float4*)attn)[(h << 4) + (lane & 15)];
    float p = a.x * av.x + a.y * av.y + a.z * av.z + a.w * av.w;
    p += __shfl_xor(p, 1);
    p += __shfl_xor(p, 2);
    p += __shfl_xor(p, 4);
    p += __shfl_xor(p, 8);
    if ((lane & 15) == 0) score[(row << 2) + h] = p;
}

// ---------------------------------------------------------------------------
// CSR build: histogram -> scan -> fill
// ---------------------------------------------------------------------------
__global__ void hist_kernel(const int* __restrict__ e1_dst,
                            const int* __restrict__ e2_dst,
                            int* __restrict__ counts)
{
    int i = blockIdx.x * blockDim.x + threadIdx.x;
    if (i < NE1) atomicAdd(&counts[e1_dst[i]], 1);
    else if (i < NE) atomicAdd(&counts[e2_dst[i - NE1]], 1);
}

__global__ __launch_bounds__(1024) void scan_kernel(
    const int* __restrict__ counts,
    int* __restrict__ offsets,
    int* __restrict__ cursor)
{
    __shared__ int sums[1024];
    const int t = threadIdx.x;
    const int C = 98;  // 1024*98 = 100352 >= NM
    const int lo = t * C;
    const int hi = min(lo + C, NM);
    int s = 0;
    for (int i = lo; i < hi; ++i) s += counts[i];
    sums[t] = s;
    __syncthreads();
    // Hillis-Steele inclusive scan
    for (int off = 1; off < 1024; off <<= 1) {
        int u = (t >= off) ? sums[t - off] : 0;
        __syncthreads();
        sums[t] += u;
        __syncthreads();
    }
    int run = (t == 0) ? 0 : sums[t - 1];
    for (int i = lo; i < hi; ++i) {
        offsets[i] = run;
        cursor[i]  = run;
        run += counts[i];
    }
    if (t == 1023) offsets[NM] = sums[1023];
}

__global__ void fill_kernel(const int* __restrict__ e1_src,
                            const int* __restrict__ e1_dst,
                            const int* __restrict__ e2_src,
                            const int* __restrict__ e2_dst,
                            int* __restrict__ cursor,
                            int* __restrict__ sorted)
{
    int i = blockIdx.x * blockDim.x + threadIdx.x;
    if (i >= NE) return;
    int dst, enc;
    if (i < NE1) { dst = e1_dst[i]; enc = e1_src[i]; }
    else         { int j = i - NE1; dst = e2_dst[j]; enc = e2_src[j] | (1 << 30); }
    int p = atomicAdd(&cursor[dst], 1);
    sorted[p] = enc;
}

// ---------------------------------------------------------------------------
// Aggregation: one block (256 threads) per master node.
// Pass 1: per-head max of leaky_relu(el_src + er_dst) over incoming edges.
// Pass 2: s = sum exp(v-m); acc = sum ft_src[h][d] * exp(v-m). out = acc/s.
// ---------------------------------------------------------------------------
__global__ __launch_bounds__(256) void aggregate_kernel(
    const int* __restrict__ offsets,
    const int* __restrict__ sorted,
    const float* __restrict__ er,    // (NM,4)
    const float* __restrict__ el_b,  // (NB,4)
    const float* __restrict__ el_g,  // (NG,4)
    const float* __restrict__ ft_b,  // (NB,256)
    const float* __restrict__ ft_g,  // (NG,256)
    float* __restrict__ out)         // (NM,256)
{
    const int n   = blockIdx.x;
    const int tid = threadIdx.x;
    const int h   = tid >> 6;
    const int start = offsets[n];
    const int end   = offsets[n + 1];
    const float rn  = er[(n << 2) + h];

    float m = -1e30f;
    for (int e = start; e < end; ++e) {
        const int enc = sorted[e];
        const int isg = enc >> 30;
        const int src = enc & 0x3FFFFFFF;
        const float lv = isg ? el_g[(src << 2) + h] : el_b[(src << 2) + h];
        float v = lv + rn;
        v = v > 0.f ? v : 0.2f * v;
        m = fmaxf(m, v);
    }

    float s = 0.f, acc = 0.f;
    for (int e = start; e < end; ++e) {
        const int enc = sorted[e];
        const int isg = enc >> 30;
        const int src = enc & 0x3FFFFFFF;
        const float lv = isg ? el_g[(src << 2) + h] : el_b[(src << 2) + h];
        float v = lv + rn;
        v = v > 0.f ? v : 0.2f * v;
        const float wgt = __expf(v - m);
        s += wgt;
        const float* ft = isg ? &ft_g[(size_t)src << 8] : &ft_b[(size_t)src << 8];
        acc = fmaf(ft[tid], wgt, acc);
    }
    out[((size_t)n << 8) + tid] = (end > start) ? (acc / s) : 0.f;
}

// ---------------------------------------------------------------------------
extern "C" void kernel_launch(void* const* d_in, const int* in_sizes, int n_in,
                              void* d_out, int out_size, void* d_ws, size_t ws_size,
                              hipStream_t stream)
{
    const float* master = (const float*)d_in[0];
    const float* bond   = (const float*)d_in[1];
    const float* glob   = (const float*)d_in[2];
    const float* aW0 = (const float*)d_in[3];
    const float* ab0 = (const float*)d_in[4];
    const float* aW1 = (const float*)d_in[5];
    const float* ab1 = (const float*)d_in[6];
    const float* aW2 = (const float*)d_in[7];
    const float* bW0 = (const float*)d_in[8];
    const float* bb0 = (const float*)d_in[9];
    const float* bW1 = (const float*)d_in[10];
    const float* bb1 = (const float*)d_in[11];
    const float* bW2 = (const float*)d_in[12];
    const float* gW0 = (const float*)d_in[13];
    const float* gb0 = (const float*)d_in[14];
    const float* gW1 = (const float*)d_in[15];
    const float* gb1 = (const float*)d_in[16];
    const float* gW2 = (const float*)d_in[17];
    const float* attn_l = (const float*)d_in[18];
    const float* attn_r = (const float*)d_in[19];
    const int* e1_src = (const int*)d_in[20];
    const int* e1_dst = (const int*)d_in[21];
    const int* e2_src = (const int*)d_in[22];
    const int* e2_dst = (const int*)d_in[23];
    float* out = (float*)d_out;

    // workspace layout (floats)
    float* ws   = (float*)d_ws;
    float* ft_b = ws;                              // NB*256
    float* ft_g = ft_b + (size_t)NB * 256;         // NG*256
    float* er   = ft_g + (size_t)NG * 256;         // NM*4
    float* el_b = er + (size_t)NM * 4;             // NB*4
    float* el_g = el_b + (size_t)NB * 4;           // NG*4
    int* counts  = (int*)(el_g + (size_t)NG * 4);  // NM+1
    int* offsets = counts + (NM + 1);              // NM+1
    int* cursor  = offsets + (NM + 1);             // NM+1
    int* sorted  = cursor + (NM + 1);              // NE

    hipMemsetAsync(counts, 0, sizeof(int) * NM, stream);

    mlp_kernel<<<NM / 4, 256, 0, stream>>>(master, aW0, ab0, aW1, ab1, aW2,
                                           attn_r, er, nullptr);
    mlp_kernel<<<NB / 4, 256, 0, stream>>>(bond, bW0, bb0, bW1, bb1, bW2,
                                           attn_l, el_b, ft_b);
    mlp_kernel<<<NG / 4, 256, 0, stream>>>(glob, gW0, gb0, gW1, gb1, gW2,
                                           attn_l, el_g, ft_g);

    hist_kernel<<<(NE + 255) / 256, 256, 0, stream>>>(e1_dst, e2_dst, counts);
    scan_kernel<<<1, 1024, 0, stream>>>(counts, offsets, cursor);
    fill_kernel<<<(NE + 255) / 256, 256, 0, stream>>>(e1_src, e1_dst, e2_src, e2_dst,
                                                      cursor, sorted);
    aggregate_kernel<<<NM, 256, 0, stream>>>(offsets, sorted, er, el_b, el_g,
                                             ft_b, ft_g, out);
}

// Round 2
// 618.307 us; speedup vs baseline: 2.2196x; 2.2196x over previous
//
#include <hip/hip_runtime.h>

#define NM 100000
#define NB 200000
#define NG 5000
#define NE1 400000
#define NE2 100000
#define NE (NE1 + NE2)
#define NMP 100004  // NM+1 rounded up to keep 16B alignment of later ws regions

typedef __attribute__((ext_vector_type(8))) short bf16x8;
typedef __attribute__((ext_vector_type(4))) short short4v;
typedef __attribute__((ext_vector_type(4))) float f32x4;

__device__ __forceinline__ unsigned short f2bf(float f) {
    unsigned int u = __float_as_uint(f);
    u += 0x7FFFu + ((u >> 16) & 1u);   // round-to-nearest-even
    return (unsigned short)(u >> 16);
}
__device__ __forceinline__ float elu_f(float x) {
    return x > 0.f ? x : __expf(x) - 1.f;
}
// swizzled LDS address: activation tile row j (128B), 16B-slot XOR by (j&7)
__device__ __forceinline__ char* swz(char* base, int j, int byteoff) {
    return base + j * 128 + ((((byteoff >> 4) ^ (j & 7)) << 4) | (byteoff & 15));
}

// ---------------------------------------------------------------------------
// Weight prep: Wt[i][k] = bf16(W[k][i]); K is always 64.
// ---------------------------------------------------------------------------
__global__ void wprep_kernel(const float* __restrict__ W, short* __restrict__ Wt, int I)
{
    int idx = blockIdx.x * blockDim.x + threadIdx.x;
    if (idx >= 64 * I) return;
    int i = idx >> 6, k = idx & 63;
    Wt[idx] = (short)f2bf(W[k * I + i]);
}

// ---------------------------------------------------------------------------
// Fused 3-layer MLP via bf16 MFMA, transposed-product formulation.
// Block = 256 thr = 4 waves, tile = 64 rows. Wave w owns output-feature block:
//   layers 1/2: i in [16w,16w+16); layer 3: i in [64w,64w+64)  (h = w).
// Activations live in LDS as [j(sample)][k(feat)] bf16, XOR-swizzled.
// ---------------------------------------------------------------------------
__global__ __launch_bounds__(256) void mlp_mfma_kernel(
    const float* __restrict__ x, int N,
    const short* __restrict__ W0t, const float* __restrict__ b0,
    const short* __restrict__ W1t, const float* __restrict__ b1,
    const short* __restrict__ W2t,
    const float* __restrict__ attn,   // (4,64) f32
    float* __restrict__ score,        // (N,4)
    float* __restrict__ ft_out)       // (N,256) or nullptr
{
    __shared__ __attribute__((aligned(128))) char ldsA[64 * 128];
    __shared__ __attribute__((aligned(128))) char ldsB[64 * 128];

    const int tid = threadIdx.x;
    const int w = tid >> 6, l = tid & 63;
    const int g = l >> 4, c = l & 15;
    const int r0 = blockIdx.x << 6;

    // ---- stage x tile: f32 -> bf16, swizzled [j][k] ----
    {
        const int j = tid >> 2, q = tid & 3;
        const int row = r0 + j;
        bf16x8 o0 = (bf16x8)0, o1 = (bf16x8)0;
        if (row < N) {
            const float4* xp = (const float4*)(x + ((size_t)row << 6) + (q << 4));
            #pragma unroll
            for (int u = 0; u < 2; ++u) {
                float4 v = xp[u];
                o0[u*4+0] = (short)f2bf(v.x); o0[u*4+1] = (short)f2bf(v.y);
                o0[u*4+2] = (short)f2bf(v.z); o0[u*4+3] = (short)f2bf(v.w);
            }
            #pragma unroll
            for (int u = 0; u < 2; ++u) {
                float4 v = xp[u + 2];
                o1[u*4+0] = (short)f2bf(v.x); o1[u*4+1] = (short)f2bf(v.y);
                o1[u*4+2] = (short)f2bf(v.z); o1[u*4+3] = (short)f2bf(v.w);
            }
        }
        *(bf16x8*)swz(ldsA, j, q * 32)      = o0;
        *(bf16x8*)swz(ldsA, j, q * 32 + 16) = o1;
    }
    __syncthreads();

    // ---- layers 1 and 2 (64->64, ELU) ----
    char* src = ldsA;
    char* dst = ldsB;
    #pragma unroll
    for (int layer = 0; layer < 2; ++layer) {
        const short* Wt = layer ? W1t : W0t;
        const float* bb = layer ? b1 : b0;
        f32x4 acc[4] = {};
        #pragma unroll
        for (int step = 0; step < 2; ++step) {
            bf16x8 a = *(const bf16x8*)(Wt + (((16 * w + c) << 6) + 32 * step + 8 * g));
            #pragma unroll
            for (int t = 0; t < 4; ++t) {
                const int j = 16 * t + c;
                bf16x8 b = *(const bf16x8*)swz(src, j, 64 * step + 16 * g);
                acc[t] = __builtin_amdgcn_mfma_f32_16x16x32_bf16(a, b, acc[t], 0, 0, 0);
            }
        }
        const int i0 = 16 * w + 4 * g;
        const float4 bias = *(const float4*)(bb + i0);
        #pragma unroll
        for (int t = 0; t < 4; ++t) {
            const int j = 16 * t + c;
            short4v o;
            o[0] = (short)f2bf(elu_f(acc[t][0] + bias.x));
            o[1] = (short)f2bf(elu_f(acc[t][1] + bias.y));
            o[2] = (short)f2bf(elu_f(acc[t][2] + bias.z));
            o[3] = (short)f2bf(elu_f(acc[t][3] + bias.w));
            *(short4v*)swz(dst, j, 32 * w + 8 * g) = o;
        }
        __syncthreads();
        char* tmp = src; src = dst; dst = tmp;
    }
    // activations for layer 3 now in `src`

    // ---- layer 3 (64->256, identity, no bias) + scores ----
    {
        f32x4 acc[4][4] = {};  // [it][t]
        #pragma unroll
        for (int step = 0; step < 2; ++step) {
            bf16x8 bfr[4];
            #pragma unroll
            for (int t = 0; t < 4; ++t)
                bfr[t] = *(const bf16x8*)swz(src, 16 * t + c, 64 * step + 16 * g);
            #pragma unroll
            for (int it = 0; it < 4; ++it) {
                bf16x8 a = *(const bf16x8*)(W2t + (((64 * w + 16 * it + c) << 6) + 32 * step + 8 * g));
                #pragma unroll
                for (int t = 0; t < 4; ++t)
                    acc[it][t] = __builtin_amdgcn_mfma_f32_16x16x32_bf16(a, bfr[t], acc[it][t], 0, 0, 0);
            }
        }
        float4 av[4];
        #pragma unroll
        for (int it = 0; it < 4; ++it)
            av[it] = *(const float4*)(attn + 64 * w + 16 * it + 4 * g);

        #pragma unroll
        for (int t = 0; t < 4; ++t) {
            const int row = r0 + 16 * t + c;
            float p = 0.f;
            #pragma unroll
            for (int it = 0; it < 4; ++it) {
                p += acc[it][t][0] * av[it].x + acc[it][t][1] * av[it].y
                   + acc[it][t][2] * av[it].z + acc[it][t][3] * av[it].w;
            }
            p += __shfl_xor(p, 16);
            p += __shfl_xor(p, 32);
            if (row < N) {
                if (g == 0) score[(row << 2) + w] = p;
                if (ft_out) {
                    #pragma unroll
                    for (int it = 0; it < 4; ++it)
                        *(f32x4*)(ft_out + ((size_t)row << 8) + 64 * w + 16 * it + 4 * g) = acc[it][t];
                }
            }
        }
    }
}

// ---------------------------------------------------------------------------
// CSR build: histogram -> scan -> fill
// ---------------------------------------------------------------------------
__global__ void hist_kernel(const int* __restrict__ e1_dst,
                            const int* __restrict__ e2_dst,
                            int* __restrict__ counts)
{
    int i = blockIdx.x * blockDim.x + threadIdx.x;
    if (i < NE1) atomicAdd(&counts[e1_dst[i]], 1);
    else if (i < NE) atomicAdd(&counts[e2_dst[i - NE1]], 1);
}

__global__ __launch_bounds__(1024) void scan_kernel(
    const int* __restrict__ counts,
    int* __restrict__ offsets,
    int* __restrict__ cursor)
{
    __shared__ int sums[1024];
    const int t = threadIdx.x;
    const int C = 98;  // 1024*98 >= NM
    const int lo = t * C;
    const int hi = min(lo + C, NM);
    int s = 0;
    for (int i = lo; i < hi; ++i) s += counts[i];
    sums[t] = s;
    __syncthreads();
    for (int off = 1; off < 1024; off <<= 1) {
        int u = (t >= off) ? sums[t - off] : 0;
        __syncthreads();
        sums[t] += u;
        __syncthreads();
    }
    int run = (t == 0) ? 0 : sums[t - 1];
    for (int i = lo; i < hi; ++i) {
        offsets[i] = run;
        cursor[i]  = run;
        run += counts[i];
    }
    if (t == 1023) offsets[NM] = sums[1023];
}

__global__ void fill_kernel(const int* __restrict__ e1_src,
                            const int* __restrict__ e1_dst,
                            const int* __restrict__ e2_src,
                            const int* __restrict__ e2_dst,
                            int* __restrict__ cursor,
                            int* __restrict__ sorted)
{
    int i = blockIdx.x * blockDim.x + threadIdx.x;
    if (i >= NE) return;
    int dst, enc;
    if (i < NE1) { dst = e1_dst[i]; enc = e1_src[i]; }
    else         { int j = i - NE1; dst = e2_dst[j]; enc = e2_src[j] | (1 << 30); }
    int p = atomicAdd(&cursor[dst], 1);
    sorted[p] = enc;
}

// ---------------------------------------------------------------------------
// Aggregation: one block (256 threads) per master node (unchanged this round).
// ---------------------------------------------------------------------------
__global__ __launch_bounds__(256) void aggregate_kernel(
    const int* __restrict__ offsets,
    const int* __restrict__ sorted,
    const float* __restrict__ er,
    const float* __restrict__ el_b,
    const float* __restrict__ el_g,
    const float* __restrict__ ft_b,
    const float* __restrict__ ft_g,
    float* __restrict__ out)
{
    const int n   = blockIdx.x;
    const int tid = threadIdx.x;
    const int h   = tid >> 6;
    const int start = offsets[n];
    const int end   = offsets[n + 1];
    const float rn  = er[(n << 2) + h];

    float m = -1e30f;
    for (int e = start; e < end; ++e) {
        const int enc = sorted[e];
        const int isg = enc >> 30;
        const int src = enc & 0x3FFFFFFF;
        const float lv = isg ? el_g[(src << 2) + h] : el_b[(src << 2) + h];
        float v = lv + rn;
        v = v > 0.f ? v : 0.2f * v;
        m = fmaxf(m, v);
    }

    float s = 0.f, acc = 0.f;
    for (int e = start; e < end; ++e) {
        const int enc = sorted[e];
        const int isg = enc >> 30;
        const int src = enc & 0x3FFFFFFF;
        const float lv = isg ? el_g[(src << 2) + h] : el_b[(src << 2) + h];
        float v = lv + rn;
        v = v > 0.f ? v : 0.2f * v;
        const float wgt = __expf(v - m);
        s += wgt;
        const float* ft = isg ? &ft_g[(size_t)src << 8] : &ft_b[(size_t)src << 8];
        acc = fmaf(ft[tid], wgt, acc);
    }
    out[((size_t)n << 8) + tid] = (end > start) ? (acc / s) : 0.f;
}

// ---------------------------------------------------------------------------
extern "C" void kernel_launch(void* const* d_in, const int* in_sizes, int n_in,
                              void* d_out, int out_size, void* d_ws, size_t ws_size,
                              hipStream_t stream)
{
    const float* master = (const float*)d_in[0];
    const float* bond   = (const float*)d_in[1];
    const float* glob   = (const float*)d_in[2];
    const float* aW0 = (const float*)d_in[3];
    const float* ab0 = (const float*)d_in[4];
    const float* aW1 = (const float*)d_in[5];
    const float* ab1 = (const float*)d_in[6];
    const float* aW2 = (const float*)d_in[7];
    const float* bW0 = (const float*)d_in[8];
    const float* bb0 = (const float*)d_in[9];
    const float* bW1 = (const float*)d_in[10];
    const float* bb1 = (const float*)d_in[11];
    const float* bW2 = (const float*)d_in[12];
    const float* gW0 = (const float*)d_in[13];
    const float* gb0 = (const float*)d_in[14];
    const float* gW1 = (const float*)d_in[15];
    const float* gb1 = (const float*)d_in[16];
    const float* gW2 = (const float*)d_in[17];
    const float* attn_l = (const float*)d_in[18];
    const float* attn_r = (const float*)d_in[19];
    const int* e1_src = (const int*)d_in[20];
    const int* e1_dst = (const int*)d_in[21];
    const int* e2_src = (const int*)d_in[22];
    const int* e2_dst = (const int*)d_in[23];
    float* out = (float*)d_out;

    // workspace layout
    float* ws   = (float*)d_ws;
    float* ft_b = ws;                              // NB*256 f32
    float* ft_g = ft_b + (size_t)NB * 256;         // NG*256
    float* er   = ft_g + (size_t)NG * 256;         // NM*4
    float* el_b = er + (size_t)NM * 4;             // NB*4
    float* el_g = el_b + (size_t)NB * 4;           // NG*4
    int* counts  = (int*)(el_g + (size_t)NG * 4);  // NMP
    int* offsets = counts + NMP;                   // NMP
    int* cursor  = offsets + NMP;                  // NMP
    int* sorted  = cursor + NMP;                   // NE
    short* wtA = (short*)(sorted + NE);            // 24576 shorts (atom)
    short* wtB = wtA + 24576;                      // bond
    short* wtG = wtB + 24576;                      // glob

    hipMemsetAsync(counts, 0, sizeof(int) * NM, stream);

    // weight transpose+bf16 prep (Wt layout: [i][k], K=64)
    wprep_kernel<<<16, 256, 0, stream>>>(aW0, wtA,          64);
    wprep_kernel<<<16, 256, 0, stream>>>(aW1, wtA + 4096,   64);
    wprep_kernel<<<64, 256, 0, stream>>>(aW2, wtA + 8192,  256);
    wprep_kernel<<<16, 256, 0, stream>>>(bW0, wtB,          64);
    wprep_kernel<<<16, 256, 0, stream>>>(bW1, wtB + 4096,   64);
    wprep_kernel<<<64, 256, 0, stream>>>(bW2, wtB + 8192,  256);
    wprep_kernel<<<16, 256, 0, stream>>>(gW0, wtG,          64);
    wprep_kernel<<<16, 256, 0, stream>>>(gW1, wtG + 4096,   64);
    wprep_kernel<<<64, 256, 0, stream>>>(gW2, wtG + 8192,  256);

    mlp_mfma_kernel<<<(NM + 63) / 64, 256, 0, stream>>>(
        master, NM, wtA, ab0, wtA + 4096, ab1, wtA + 8192, attn_r, er, nullptr);
    mlp_mfma_kernel<<<(NB + 63) / 64, 256, 0, stream>>>(
        bond, NB, wtB, bb0, wtB + 4096, bb1, wtB + 8192, attn_l, el_b, ft_b);
    mlp_mfma_kernel<<<(NG + 63) / 64, 256, 0, stream>>>(
        glob, NG, wtG, gb0, wtG + 4096, gb1, wtG + 8192, attn_l, el_g, ft_g);

    hist_kernel<<<(NE + 255) / 256, 256, 0, stream>>>(e1_dst, e2_dst, counts);
    scan_kernel<<<1, 1024, 0, stream>>>(counts, offsets, cursor);
    fill_kernel<<<(NE + 255) / 256, 256, 0, stream>>>(e1_src, e1_dst, e2_src, e2_dst,
                                                      cursor, sorted);
    aggregate_kernel<<<NM, 256, 0, stream>>>(offsets, sorted, er, el_b, el_g,
                                             ft_b, ft_g, out);
}

// Round 3
// 539.329 us; speedup vs baseline: 2.5446x; 1.1464x over previous
//
#include <hip/hip_runtime.h>

#define NM 100000
#define NB 200000
#define NG 5000
#define NE1 400000
#define NE2 100000
#define NE (NE1 + NE2)
#define NMP 100004  // NM+1 rounded up to keep 16B alignment of later ws regions

typedef __attribute__((ext_vector_type(8))) short bf16x8;
typedef __attribute__((ext_vector_type(4))) short short4v;
typedef __attribute__((ext_vector_type(4))) float f32x4;

__device__ __forceinline__ unsigned short f2bf(float f) {
    unsigned int u = __float_as_uint(f);
    u += 0x7FFFu + ((u >> 16) & 1u);   // round-to-nearest-even
    return (unsigned short)(u >> 16);
}
__device__ __forceinline__ float bf2f(unsigned short u) {
    return __uint_as_float((unsigned int)u << 16);
}
__device__ __forceinline__ float elu_f(float x) {
    return x > 0.f ? x : __expf(x) - 1.f;
}
// swizzled LDS address: activation tile row j (128B), 16B-slot XOR by (j&7)
__device__ __forceinline__ char* swz(char* base, int j, int byteoff) {
    return base + j * 128 + ((((byteoff >> 4) ^ (j & 7)) << 4) | (byteoff & 15));
}

// ---------------------------------------------------------------------------
// Weight prep (all 9 matrices in one launch): Wt[i][k] = bf16(W[k][i]), K=64.
// ---------------------------------------------------------------------------
struct WEnt { const float* W; short* o; int I; int off; };
struct WAll { WEnt e[9]; };

__global__ __launch_bounds__(256) void wprep_all_kernel(WAll a)
{
    const int idx = blockIdx.x * 256 + threadIdx.x;  // grid sized exactly
    #pragma unroll
    for (int j = 8; j >= 0; --j) {
        if (idx >= a.e[j].off) {
            const int local = idx - a.e[j].off;
            const int I = a.e[j].I;
            const int i = local >> 6, k = local & 63;
            a.e[j].o[local] = (short)f2bf(a.e[j].W[k * I + i]);
            break;
        }
    }
}

// ---------------------------------------------------------------------------
// Fused 3-layer MLP via bf16 MFMA, transposed-product formulation.
// Block = 256 thr = 4 waves, tile = 64 rows. Wave w owns output-feature block:
//   layers 1/2: i in [16w,16w+16); layer 3: i in [64w,64w+64)  (h = w).
// Activations live in LDS as [j(sample)][k(feat)] bf16, XOR-swizzled.
// ft_out (bf16) may be nullptr (master nodes).
// ---------------------------------------------------------------------------
__global__ __launch_bounds__(256) void mlp_mfma_kernel(
    const float* __restrict__ x, int N,
    const short* __restrict__ W0t, const float* __restrict__ b0,
    const short* __restrict__ W1t, const float* __restrict__ b1,
    const short* __restrict__ W2t,
    const float* __restrict__ attn,    // (4,64) f32
    float* __restrict__ score,         // (N,4)
    unsigned short* __restrict__ ft_out) // (N,256) bf16 or nullptr
{
    __shared__ __attribute__((aligned(128))) char ldsA[64 * 128];
    __shared__ __attribute__((aligned(128))) char ldsB[64 * 128];

    const int tid = threadIdx.x;
    const int w = tid >> 6, l = tid & 63;
    const int g = l >> 4, c = l & 15;
    const int r0 = blockIdx.x << 6;

    // ---- stage x tile: f32 -> bf16, swizzled [j][k] ----
    {
        const int j = tid >> 2, q = tid & 3;
        const int row = r0 + j;
        bf16x8 o0 = (bf16x8)0, o1 = (bf16x8)0;
        if (row < N) {
            const float4* xp = (const float4*)(x + ((size_t)row << 6) + (q << 4));
            #pragma unroll
            for (int u = 0; u < 2; ++u) {
                float4 v = xp[u];
                o0[u*4+0] = (short)f2bf(v.x); o0[u*4+1] = (short)f2bf(v.y);
                o0[u*4+2] = (short)f2bf(v.z); o0[u*4+3] = (short)f2bf(v.w);
            }
            #pragma unroll
            for (int u = 0; u < 2; ++u) {
                float4 v = xp[u + 2];
                o1[u*4+0] = (short)f2bf(v.x); o1[u*4+1] = (short)f2bf(v.y);
                o1[u*4+2] = (short)f2bf(v.z); o1[u*4+3] = (short)f2bf(v.w);
            }
        }
        *(bf16x8*)swz(ldsA, j, q * 32)      = o0;
        *(bf16x8*)swz(ldsA, j, q * 32 + 16) = o1;
    }
    __syncthreads();

    // ---- layers 1 and 2 (64->64, ELU) ----
    char* src = ldsA;
    char* dst = ldsB;
    #pragma unroll
    for (int layer = 0; layer < 2; ++layer) {
        const short* Wt = layer ? W1t : W0t;
        const float* bb = layer ? b1 : b0;
        f32x4 acc[4] = {};
        #pragma unroll
        for (int step = 0; step < 2; ++step) {
            bf16x8 a = *(const bf16x8*)(Wt + (((16 * w + c) << 6) + 32 * step + 8 * g));
            #pragma unroll
            for (int t = 0; t < 4; ++t) {
                const int j = 16 * t + c;
                bf16x8 b = *(const bf16x8*)swz(src, j, 64 * step + 16 * g);
                acc[t] = __builtin_amdgcn_mfma_f32_16x16x32_bf16(a, b, acc[t], 0, 0, 0);
            }
        }
        const int i0 = 16 * w + 4 * g;
        const float4 bias = *(const float4*)(bb + i0);
        #pragma unroll
        for (int t = 0; t < 4; ++t) {
            const int j = 16 * t + c;
            short4v o;
            o[0] = (short)f2bf(elu_f(acc[t][0] + bias.x));
            o[1] = (short)f2bf(elu_f(acc[t][1] + bias.y));
            o[2] = (short)f2bf(elu_f(acc[t][2] + bias.z));
            o[3] = (short)f2bf(elu_f(acc[t][3] + bias.w));
            *(short4v*)swz(dst, j, 32 * w + 8 * g) = o;
        }
        __syncthreads();
        char* tmp = src; src = dst; dst = tmp;
    }
    // activations for layer 3 now in `src`

    // ---- layer 3 (64->256, identity, no bias) + scores ----
    {
        f32x4 acc[4][4] = {};  // [it][t]
        #pragma unroll
        for (int step = 0; step < 2; ++step) {
            bf16x8 bfr[4];
            #pragma unroll
            for (int t = 0; t < 4; ++t)
                bfr[t] = *(const bf16x8*)swz(src, 16 * t + c, 64 * step + 16 * g);
            #pragma unroll
            for (int it = 0; it < 4; ++it) {
                bf16x8 a = *(const bf16x8*)(W2t + (((64 * w + 16 * it + c) << 6) + 32 * step + 8 * g));
                #pragma unroll
                for (int t = 0; t < 4; ++t)
                    acc[it][t] = __builtin_amdgcn_mfma_f32_16x16x32_bf16(a, bfr[t], acc[it][t], 0, 0, 0);
            }
        }
        float4 av[4];
        #pragma unroll
        for (int it = 0; it < 4; ++it)
            av[it] = *(const float4*)(attn + 64 * w + 16 * it + 4 * g);

        #pragma unroll
        for (int t = 0; t < 4; ++t) {
            const int row = r0 + 16 * t + c;
            float p = 0.f;
            #pragma unroll
            for (int it = 0; it < 4; ++it) {
                p += acc[it][t][0] * av[it].x + acc[it][t][1] * av[it].y
                   + acc[it][t][2] * av[it].z + acc[it][t][3] * av[it].w;
            }
            p += __shfl_xor(p, 16);
            p += __shfl_xor(p, 32);
            if (row < N) {
                if (g == 0) score[(row << 2) + w] = p;
                if (ft_out) {
                    #pragma unroll
                    for (int it = 0; it < 4; ++it) {
                        short4v o;
                        o[0] = (short)f2bf(acc[it][t][0]);
                        o[1] = (short)f2bf(acc[it][t][1]);
                        o[2] = (short)f2bf(acc[it][t][2]);
                        o[3] = (short)f2bf(acc[it][t][3]);
                        *(short4v*)(ft_out + ((size_t)row << 8) + 64 * w + 16 * it + 4 * g) = o;
                    }
                }
            }
        }
    }
}

// ---------------------------------------------------------------------------
// CSR build: histogram -> scan -> fill (+ per-edge logits)
// ---------------------------------------------------------------------------
__global__ void hist_kernel(const int* __restrict__ e1_dst,
                            const int* __restrict__ e2_dst,
                            int* __restrict__ counts)
{
    int i = blockIdx.x * blockDim.x + threadIdx.x;
    if (i < NE1) atomicAdd(&counts[e1_dst[i]], 1);
    else if (i < NE) atomicAdd(&counts[e2_dst[i - NE1]], 1);
}

__global__ __launch_bounds__(1024) void scan_kernel(
    const int* __restrict__ counts,
    int* __restrict__ offsets,
    int* __restrict__ cursor)
{
    __shared__ int sums[1024];
    const int t = threadIdx.x;
    const int C = 98;  // 1024*98 >= NM
    const int lo = t * C;
    const int hi = min(lo + C, NM);
    int s = 0;
    for (int i = lo; i < hi; ++i) s += counts[i];
    sums[t] = s;
    __syncthreads();
    for (int off = 1; off < 1024; off <<= 1) {
        int u = (t >= off) ? sums[t - off] : 0;
        __syncthreads();
        sums[t] += u;
        __syncthreads();
    }
    int run = (t == 0) ? 0 : sums[t - 1];
    for (int i = lo; i < hi; ++i) {
        offsets[i] = run;
        cursor[i]  = run;
        run += counts[i];
    }
    if (t == 1023) offsets[NM] = sums[1023];
}

// fill: place edge into CSR slot AND compute v = leaky(el[src] + er[dst]) (4 heads)
__global__ void fill_kernel(const int* __restrict__ e1_src,
                            const int* __restrict__ e1_dst,
                            const int* __restrict__ e2_src,
                            const int* __restrict__ e2_dst,
                            const float* __restrict__ er,
                            const float* __restrict__ el_b,
                            const float* __restrict__ el_g,
                            int* __restrict__ cursor,
                            int* __restrict__ sorted,
                            float4* __restrict__ vsort)
{
    int i = blockIdx.x * blockDim.x + threadIdx.x;
    if (i >= NE) return;
    int dst, src, enc;
    const float* el;
    if (i < NE1) { src = e1_src[i]; dst = e1_dst[i]; enc = src;              el = el_b; }
    else { int j = i - NE1; src = e2_src[j]; dst = e2_dst[j]; enc = src | (1 << 30); el = el_g; }
    const float4 l4 = *(const float4*)(el + (src << 2));
    const float4 r4 = *(const float4*)(er + (dst << 2));
    float4 v;
    v.x = l4.x + r4.x; v.x = v.x > 0.f ? v.x : 0.2f * v.x;
    v.y = l4.y + r4.y; v.y = v.y > 0.f ? v.y : 0.2f * v.y;
    v.z = l4.z + r4.z; v.z = v.z > 0.f ? v.z : 0.2f * v.z;
    v.w = l4.w + r4.w; v.w = v.w > 0.f ? v.w : 0.2f * v.w;
    int p = atomicAdd(&cursor[dst], 1);
    sorted[p] = enc;
    vsort[p] = v;
}

// ---------------------------------------------------------------------------
// Aggregation: grid-stride over nodes; block = 256 thr = 4 waves, wave = head.
// Lane-parallel max & exp-sum over the segment's precomputed logits, then one
// pass of weighted bf16 ft accumulation.
// ---------------------------------------------------------------------------
__global__ __launch_bounds__(256) void aggregate_kernel(
    const int* __restrict__ offsets,
    const int* __restrict__ sorted,
    const float* __restrict__ vsort,       // (NE,4)
    const unsigned short* __restrict__ ftb, // (NB,256) bf16
    const unsigned short* __restrict__ ftg, // (NG,256) bf16
    float* __restrict__ out)               // (NM,256)
{
    const int tid = threadIdx.x;
    const int w = tid >> 6, l = tid & 63;

    for (int n = blockIdx.x; n < NM; n += gridDim.x) {
        const int start = offsets[n];
        const int end   = offsets[n + 1];
        const int deg   = end - start;
        if (deg == 0) {
            out[((size_t)n << 8) + tid] = 0.f;
            continue;
        }

        // chunk 0 logit in register; rare extra chunks via loads
        float v0 = (l < deg) ? vsort[((start + l) << 2) + w] : -1e30f;
        float m = v0;
        for (int base = 64; base < deg; base += 64) {
            int e = base + l;
            if (e < deg) m = fmaxf(m, vsort[((start + e) << 2) + w]);
        }
        #pragma unroll
        for (int o = 1; o < 64; o <<= 1) m = fmaxf(m, __shfl_xor(m, o));

        float ev0 = (l < deg) ? __expf(v0 - m) : 0.f;
        float s = ev0;
        for (int base = 64; base < deg; base += 64) {
            int e = base + l;
            if (e < deg) s += __expf(vsort[((start + e) << 2) + w] - m);
        }
        #pragma unroll
        for (int o = 1; o < 64; o <<= 1) s += __shfl_xor(s, o);
        const float inv_s = 1.f / s;

        float acc = 0.f;
        for (int e = 0; e < deg; ++e) {
            const int enc = sorted[start + e];
            const int isg = enc >> 30;
            const int src = enc & 0x3FFFFFFF;
            const float wgt = (e < 64) ? __shfl(ev0, e)
                                       : __expf(vsort[((start + e) << 2) + w] - m);
            const unsigned short* ft = isg ? (ftg + ((size_t)src << 8))
                                           : (ftb + ((size_t)src << 8));
            acc = fmaf(bf2f(ft[tid]), wgt, acc);
        }
        out[((size_t)n << 8) + tid] = acc * inv_s;
    }
}

// ---------------------------------------------------------------------------
extern "C" void kernel_launch(void* const* d_in, const int* in_sizes, int n_in,
                              void* d_out, int out_size, void* d_ws, size_t ws_size,
                              hipStream_t stream)
{
    const float* master = (const float*)d_in[0];
    const float* bond   = (const float*)d_in[1];
    const float* glob   = (const float*)d_in[2];
    const float* aW0 = (const float*)d_in[3];
    const float* ab0 = (const float*)d_in[4];
    const float* aW1 = (const float*)d_in[5];
    const float* ab1 = (const float*)d_in[6];
    const float* aW2 = (const float*)d_in[7];
    const float* bW0 = (const float*)d_in[8];
    const float* bb0 = (const float*)d_in[9];
    const float* bW1 = (const float*)d_in[10];
    const float* bb1 = (const float*)d_in[11];
    const float* bW2 = (const float*)d_in[12];
    const float* gW0 = (const float*)d_in[13];
    const float* gb0 = (const float*)d_in[14];
    const float* gW1 = (const float*)d_in[15];
    const float* gb1 = (const float*)d_in[16];
    const float* gW2 = (const float*)d_in[17];
    const float* attn_l = (const float*)d_in[18];
    const float* attn_r = (const float*)d_in[19];
    const int* e1_src = (const int*)d_in[20];
    const int* e1_dst = (const int*)d_in[21];
    const int* e2_src = (const int*)d_in[22];
    const int* e2_dst = (const int*)d_in[23];
    float* out = (float*)d_out;

    // workspace layout
    float* ws   = (float*)d_ws;
    unsigned short* ft_b = (unsigned short*)ws;          // NB*256 bf16
    unsigned short* ft_g = ft_b + (size_t)NB * 256;      // NG*256 bf16
    float* er   = (float*)(ft_g + (size_t)NG * 256);     // NM*4
    float* el_b = er + (size_t)NM * 4;                   // NB*4
    float* el_g = el_b + (size_t)NB * 4;                 // NG*4
    int* counts  = (int*)(el_g + (size_t)NG * 4);        // NMP
    int* offsets = counts + NMP;                         // NMP
    int* cursor  = offsets + NMP;                        // NMP
    int* sorted  = cursor + NMP;                         // NE
    float4* vsort = (float4*)(sorted + NE);              // NE float4
    short* wtA = (short*)(vsort + NE);                   // 24576 shorts
    short* wtB = wtA + 24576;
    short* wtG = wtB + 24576;

    hipMemsetAsync(counts, 0, sizeof(int) * NM, stream);

    // fused weight prep: 9 transposed bf16 matrices, one launch
    WAll wa;
    wa.e[0] = {aW0, wtA,          64,     0};
    wa.e[1] = {aW1, wtA + 4096,   64,  4096};
    wa.e[2] = {aW2, wtA + 8192,  256,  8192};
    wa.e[3] = {bW0, wtB,          64, 24576};
    wa.e[4] = {bW1, wtB + 4096,   64, 28672};
    wa.e[5] = {bW2, wtB + 8192,  256, 32768};
    wa.e[6] = {gW0, wtG,          64, 49152};
    wa.e[7] = {gW1, wtG + 4096,   64, 53248};
    wa.e[8] = {gW2, wtG + 8192,  256, 57344};
    wprep_all_kernel<<<288, 256, 0, stream>>>(wa);

    mlp_mfma_kernel<<<(NM + 63) / 64, 256, 0, stream>>>(
        master, NM, wtA, ab0, wtA + 4096, ab1, wtA + 8192, attn_r, er, nullptr);
    mlp_mfma_kernel<<<(NB + 63) / 64, 256, 0, stream>>>(
        bond, NB, wtB, bb0, wtB + 4096, bb1, wtB + 8192, attn_l, el_b, ft_b);
    mlp_mfma_kernel<<<(NG + 63) / 64, 256, 0, stream>>>(
        glob, NG, wtG, gb0, wtG + 4096, gb1, wtG + 8192, attn_l, el_g, ft_g);

    hist_kernel<<<(NE + 255) / 256, 256, 0, stream>>>(e1_dst, e2_dst, counts);
    scan_kernel<<<1, 1024, 0, stream>>>(counts, offsets, cursor);
    fill_kernel<<<(NE + 255) / 256, 256, 0, stream>>>(e1_src, e1_dst, e2_src, e2_dst,
                                                      er, el_b, el_g,
                                                      cursor, sorted, vsort);
    aggregate_kernel<<<4096, 256, 0, stream>>>(offsets, sorted, (const float*)vsort,
                                               ft_b, ft_g, out);
}

// Round 4
// 321.147 us; speedup vs baseline: 4.2734x; 1.6794x over previous
//
#include <hip/hip_runtime.h>

#define NM 100000
#define NB 200000
#define NG 5000
#define NE1 400000
#define NE2 100000
#define NE (NE1 + NE2)
#define NMP 100004  // NM+1 rounded up to keep 16B alignment of later ws regions
#define SCAN_BLOCKS 391  // 391*256 = 100096 >= NM

typedef __attribute__((ext_vector_type(8))) short bf16x8;
typedef __attribute__((ext_vector_type(4))) short short4v;
typedef __attribute__((ext_vector_type(4))) float f32x4;

__device__ __forceinline__ unsigned short f2bf(float f) {
    unsigned int u = __float_as_uint(f);
    u += 0x7FFFu + ((u >> 16) & 1u);   // round-to-nearest-even
    return (unsigned short)(u >> 16);
}
__device__ __forceinline__ float bf2f(unsigned short u) {
    return __uint_as_float((unsigned int)u << 16);
}
__device__ __forceinline__ float elu_f(float x) {
    return x > 0.f ? x : __expf(x) - 1.f;
}
// swizzled LDS address: activation tile row j (128B), 16B-slot XOR by (j&7)
__device__ __forceinline__ char* swz(char* base, int j, int byteoff) {
    return base + j * 128 + ((((byteoff >> 4) ^ (j & 7)) << 4) | (byteoff & 15));
}

// ---------------------------------------------------------------------------
// Weight prep (all 9 matrices in one launch): Wt[i][k] = bf16(W[k][i]), K=64.
// ---------------------------------------------------------------------------
struct WEnt { const float* W; short* o; int I; int off; };
struct WAll { WEnt e[9]; };

__global__ __launch_bounds__(256) void wprep_all_kernel(WAll a)
{
    const int idx = blockIdx.x * 256 + threadIdx.x;  // grid sized exactly
    #pragma unroll
    for (int j = 8; j >= 0; --j) {
        if (idx >= a.e[j].off) {
            const int local = idx - a.e[j].off;
            const int I = a.e[j].I;
            const int i = local >> 6, k = local & 63;
            a.e[j].o[local] = (short)f2bf(a.e[j].W[k * I + i]);
            break;
        }
    }
}

// ---------------------------------------------------------------------------
// Fused 3-layer MLP via bf16 MFMA, transposed-product formulation.
// ---------------------------------------------------------------------------
__global__ __launch_bounds__(256) void mlp_mfma_kernel(
    const float* __restrict__ x, int N,
    const short* __restrict__ W0t, const float* __restrict__ b0,
    const short* __restrict__ W1t, const float* __restrict__ b1,
    const short* __restrict__ W2t,
    const float* __restrict__ attn,    // (4,64) f32
    float* __restrict__ score,         // (N,4)
    unsigned short* __restrict__ ft_out) // (N,256) bf16 or nullptr
{
    __shared__ __attribute__((aligned(128))) char ldsA[64 * 128];
    __shared__ __attribute__((aligned(128))) char ldsB[64 * 128];

    const int tid = threadIdx.x;
    const int w = tid >> 6, l = tid & 63;
    const int g = l >> 4, c = l & 15;
    const int r0 = blockIdx.x << 6;

    // ---- stage x tile: f32 -> bf16, swizzled [j][k] ----
    {
        const int j = tid >> 2, q = tid & 3;
        const int row = r0 + j;
        bf16x8 o0 = (bf16x8)0, o1 = (bf16x8)0;
        if (row < N) {
            const float4* xp = (const float4*)(x + ((size_t)row << 6) + (q << 4));
            #pragma unroll
            for (int u = 0; u < 2; ++u) {
                float4 v = xp[u];
                o0[u*4+0] = (short)f2bf(v.x); o0[u*4+1] = (short)f2bf(v.y);
                o0[u*4+2] = (short)f2bf(v.z); o0[u*4+3] = (short)f2bf(v.w);
            }
            #pragma unroll
            for (int u = 0; u < 2; ++u) {
                float4 v = xp[u + 2];
                o1[u*4+0] = (short)f2bf(v.x); o1[u*4+1] = (short)f2bf(v.y);
                o1[u*4+2] = (short)f2bf(v.z); o1[u*4+3] = (short)f2bf(v.w);
            }
        }
        *(bf16x8*)swz(ldsA, j, q * 32)      = o0;
        *(bf16x8*)swz(ldsA, j, q * 32 + 16) = o1;
    }
    __syncthreads();

    // ---- layers 1 and 2 (64->64, ELU) ----
    char* src = ldsA;
    char* dst = ldsB;
    #pragma unroll
    for (int layer = 0; layer < 2; ++layer) {
        const short* Wt = layer ? W1t : W0t;
        const float* bb = layer ? b1 : b0;
        f32x4 acc[4] = {};
        #pragma unroll
        for (int step = 0; step < 2; ++step) {
            bf16x8 a = *(const bf16x8*)(Wt + (((16 * w + c) << 6) + 32 * step + 8 * g));
            #pragma unroll
            for (int t = 0; t < 4; ++t) {
                const int j = 16 * t + c;
                bf16x8 b = *(const bf16x8*)swz(src, j, 64 * step + 16 * g);
                acc[t] = __builtin_amdgcn_mfma_f32_16x16x32_bf16(a, b, acc[t], 0, 0, 0);
            }
        }
        const int i0 = 16 * w + 4 * g;
        const float4 bias = *(const float4*)(bb + i0);
        #pragma unroll
        for (int t = 0; t < 4; ++t) {
            const int j = 16 * t + c;
            short4v o;
            o[0] = (short)f2bf(elu_f(acc[t][0] + bias.x));
            o[1] = (short)f2bf(elu_f(acc[t][1] + bias.y));
            o[2] = (short)f2bf(elu_f(acc[t][2] + bias.z));
            o[3] = (short)f2bf(elu_f(acc[t][3] + bias.w));
            *(short4v*)swz(dst, j, 32 * w + 8 * g) = o;
        }
        __syncthreads();
        char* tmp = src; src = dst; dst = tmp;
    }

    // ---- layer 3 (64->256, identity, no bias) + scores ----
    {
        f32x4 acc[4][4] = {};  // [it][t]
        #pragma unroll
        for (int step = 0; step < 2; ++step) {
            bf16x8 bfr[4];
            #pragma unroll
            for (int t = 0; t < 4; ++t)
                bfr[t] = *(const bf16x8*)swz(src, 16 * t + c, 64 * step + 16 * g);
            #pragma unroll
            for (int it = 0; it < 4; ++it) {
                bf16x8 a = *(const bf16x8*)(W2t + (((64 * w + 16 * it + c) << 6) + 32 * step + 8 * g));
                #pragma unroll
                for (int t = 0; t < 4; ++t)
                    acc[it][t] = __builtin_amdgcn_mfma_f32_16x16x32_bf16(a, bfr[t], acc[it][t], 0, 0, 0);
            }
        }
        float4 av[4];
        #pragma unroll
        for (int it = 0; it < 4; ++it)
            av[it] = *(const float4*)(attn + 64 * w + 16 * it + 4 * g);

        #pragma unroll
        for (int t = 0; t < 4; ++t) {
            const int row = r0 + 16 * t + c;
            float p = 0.f;
            #pragma unroll
            for (int it = 0; it < 4; ++it) {
                p += acc[it][t][0] * av[it].x + acc[it][t][1] * av[it].y
                   + acc[it][t][2] * av[it].z + acc[it][t][3] * av[it].w;
            }
            p += __shfl_xor(p, 16);
            p += __shfl_xor(p, 32);
            if (row < N) {
                if (g == 0) score[(row << 2) + w] = p;
                if (ft_out) {
                    #pragma unroll
                    for (int it = 0; it < 4; ++it) {
                        short4v o;
                        o[0] = (short)f2bf(acc[it][t][0]);
                        o[1] = (short)f2bf(acc[it][t][1]);
                        o[2] = (short)f2bf(acc[it][t][2]);
                        o[3] = (short)f2bf(acc[it][t][3]);
                        *(short4v*)(ft_out + ((size_t)row << 8) + 64 * w + 16 * it + 4 * g) = o;
                    }
                }
            }
        }
    }
}

// ---------------------------------------------------------------------------
// CSR build: histogram -> 3-phase parallel scan -> fill (+ per-edge logits)
// ---------------------------------------------------------------------------
__global__ void hist_kernel(const int* __restrict__ e1_dst,
                            const int* __restrict__ e2_dst,
                            int* __restrict__ counts)
{
    int i = blockIdx.x * blockDim.x + threadIdx.x;
    if (i < NE1) atomicAdd(&counts[e1_dst[i]], 1);
    else if (i < NE) atomicAdd(&counts[e2_dst[i - NE1]], 1);
}

// phase 1: per-block inclusive prefix + block totals
__global__ __launch_bounds__(256) void scan1_kernel(
    const int* __restrict__ counts,
    int* __restrict__ prefix_inc,
    int* __restrict__ blocksums)
{
    const int i = blockIdx.x * 256 + threadIdx.x;
    const int lane = threadIdx.x & 63, wv = threadIdx.x >> 6;
    int v = (i < NM) ? counts[i] : 0;
    int x = v;
    #pragma unroll
    for (int o = 1; o < 64; o <<= 1) {
        int u = __shfl_up(x, o);
        if (lane >= o) x += u;
    }
    __shared__ int wsum[4];
    if (lane == 63) wsum[wv] = x;
    __syncthreads();
    int add = 0;
    #pragma unroll
    for (int k = 0; k < 3; ++k) add += (k < wv) ? wsum[k] : 0;
    x += add;
    if (i < NM) prefix_inc[i] = x;
    if (threadIdx.x == 255) blocksums[blockIdx.x] = x;
}

// phase 2: exclusive scan of the 391 block totals (one block)
__global__ __launch_bounds__(512) void scan2_kernel(int* __restrict__ blocksums)
{
    const int t = threadIdx.x;
    const int lane = t & 63, wv = t >> 6;
    int v = (t < SCAN_BLOCKS) ? blocksums[t] : 0;
    int x = v;
    #pragma unroll
    for (int o = 1; o < 64; o <<= 1) {
        int u = __shfl_up(x, o);
        if (lane >= o) x += u;
    }
    __shared__ int wsum[8];
    if (lane == 63) wsum[wv] = x;
    __syncthreads();
    int add = 0;
    #pragma unroll
    for (int k = 0; k < 7; ++k) add += (k < wv) ? wsum[k] : 0;
    x += add;
    if (t < SCAN_BLOCKS) blocksums[t] = x - v;  // exclusive
}

// phase 3: offsets[i] = inclusive[i] - counts[i] + blockbase; init cursor
__global__ __launch_bounds__(256) void scan3_kernel(
    const int* __restrict__ counts,
    const int* __restrict__ prefix_inc,
    const int* __restrict__ blocksums,
    int* __restrict__ offsets,
    int* __restrict__ cursor)
{
    const int i = blockIdx.x * 256 + threadIdx.x;
    if (i > NM) return;
    if (i == NM) { offsets[NM] = NE; return; }
    const int off = prefix_inc[i] - counts[i] + blocksums[blockIdx.x];
    offsets[i] = off;
    cursor[i]  = off;
}

// fill: place edge into CSR slot AND compute v = leaky(el[src] + er[dst])
__global__ void fill_kernel(const int* __restrict__ e1_src,
                            const int* __restrict__ e1_dst,
                            const int* __restrict__ e2_src,
                            const int* __restrict__ e2_dst,
                            const float* __restrict__ er,
                            const float* __restrict__ el_b,
                            const float* __restrict__ el_g,
                            int* __restrict__ cursor,
                            int* __restrict__ sorted,
                            float4* __restrict__ vsort)
{
    int i = blockIdx.x * blockDim.x + threadIdx.x;
    if (i >= NE) return;
    int dst, src, enc;
    const float* el;
    if (i < NE1) { src = e1_src[i]; dst = e1_dst[i]; enc = src;              el = el_b; }
    else { int j = i - NE1; src = e2_src[j]; dst = e2_dst[j]; enc = src | (1 << 30); el = el_g; }
    const float4 l4 = *(const float4*)(el + (src << 2));
    const float4 r4 = *(const float4*)(er + (dst << 2));
    float4 v;
    v.x = l4.x + r4.x; v.x = v.x > 0.f ? v.x : 0.2f * v.x;
    v.y = l4.y + r4.y; v.y = v.y > 0.f ? v.y : 0.2f * v.y;
    v.z = l4.z + r4.z; v.z = v.z > 0.f ? v.z : 0.2f * v.z;
    v.w = l4.w + r4.w; v.w = v.w > 0.f ? v.w : 0.2f * v.w;
    int p = atomicAdd(&cursor[dst], 1);
    sorted[p] = enc;
    vsort[p] = v;
}

// ---------------------------------------------------------------------------
// Aggregation: grid-stride over nodes; block = 256 thr = 4 waves, wave = head.
// ---------------------------------------------------------------------------
__global__ __launch_bounds__(256) void aggregate_kernel(
    const int* __restrict__ offsets,
    const int* __restrict__ sorted,
    const float* __restrict__ vsort,        // (NE,4)
    const unsigned short* __restrict__ ftb, // (NB,256) bf16
    const unsigned short* __restrict__ ftg, // (NG,256) bf16
    float* __restrict__ out)                // (NM,256)
{
    const int tid = threadIdx.x;
    const int w = tid >> 6, l = tid & 63;

    for (int n = blockIdx.x; n < NM; n += gridDim.x) {
        const int start = offsets[n];
        const int end   = offsets[n + 1];
        const int deg   = end - start;
        if (deg == 0) {
            out[((size_t)n << 8) + tid] = 0.f;
            continue;
        }

        float v0 = (l < deg) ? vsort[((start + l) << 2) + w] : -1e30f;
        float m = v0;
        for (int base = 64; base < deg; base += 64) {
            int e = base + l;
            if (e < deg) m = fmaxf(m, vsort[((start + e) << 2) + w]);
        }
        #pragma unroll
        for (int o = 1; o < 64; o <<= 1) m = fmaxf(m, __shfl_xor(m, o));

        float ev0 = (l < deg) ? __expf(v0 - m) : 0.f;
        float s = ev0;
        for (int base = 64; base < deg; base += 64) {
            int e = base + l;
            if (e < deg) s += __expf(vsort[((start + e) << 2) + w] - m);
        }
        #pragma unroll
        for (int o = 1; o < 64; o <<= 1) s += __shfl_xor(s, o);
        const float inv_s = 1.f / s;

        float acc = 0.f;
        for (int e = 0; e < deg; ++e) {
            const int enc = sorted[start + e];
            const int isg = enc >> 30;
            const int src = enc & 0x3FFFFFFF;
            const float wgt = (e < 64) ? __shfl(ev0, e)
                                       : __expf(vsort[((start + e) << 2) + w] - m);
            const unsigned short* ft = isg ? (ftg + ((size_t)src << 8))
                                           : (ftb + ((size_t)src << 8));
            acc = fmaf(bf2f(ft[tid]), wgt, acc);
        }
        out[((size_t)n << 8) + tid] = acc * inv_s;
    }
}

// ---------------------------------------------------------------------------
extern "C" void kernel_launch(void* const* d_in, const int* in_sizes, int n_in,
                              void* d_out, int out_size, void* d_ws, size_t ws_size,
                              hipStream_t stream)
{
    const float* master = (const float*)d_in[0];
    const float* bond   = (const float*)d_in[1];
    const float* glob   = (const float*)d_in[2];
    const float* aW0 = (const float*)d_in[3];
    const float* ab0 = (const float*)d_in[4];
    const float* aW1 = (const float*)d_in[5];
    const float* ab1 = (const float*)d_in[6];
    const float* aW2 = (const float*)d_in[7];
    const float* bW0 = (const float*)d_in[8];
    const float* bb0 = (const float*)d_in[9];
    const float* bW1 = (const float*)d_in[10];
    const float* bb1 = (const float*)d_in[11];
    const float* bW2 = (const float*)d_in[12];
    const float* gW0 = (const float*)d_in[13];
    const float* gb0 = (const float*)d_in[14];
    const float* gW1 = (const float*)d_in[15];
    const float* gb1 = (const float*)d_in[16];
    const float* gW2 = (const float*)d_in[17];
    const float* attn_l = (const float*)d_in[18];
    const float* attn_r = (const float*)d_in[19];
    const int* e1_src = (const int*)d_in[20];
    const int* e1_dst = (const int*)d_in[21];
    const int* e2_src = (const int*)d_in[22];
    const int* e2_dst = (const int*)d_in[23];
    float* out = (float*)d_out;

    // workspace layout
    float* ws   = (float*)d_ws;
    unsigned short* ft_b = (unsigned short*)ws;          // NB*256 bf16
    unsigned short* ft_g = ft_b + (size_t)NB * 256;      // NG*256 bf16
    float* er   = (float*)(ft_g + (size_t)NG * 256);     // NM*4
    float* el_b = er + (size_t)NM * 4;                   // NB*4
    float* el_g = el_b + (size_t)NB * 4;                 // NG*4
    int* counts  = (int*)(el_g + (size_t)NG * 4);        // NMP
    int* offsets = counts + NMP;                         // NMP
    int* cursor  = offsets + NMP;                        // NMP
    int* sorted  = cursor + NMP;                         // NE
    float4* vsort = (float4*)(sorted + NE);              // NE float4 (16B-aligned: prefix is even #ints)
    int* prefix_inc = (int*)(vsort + NE);                // NMP
    int* blocksums  = prefix_inc + NMP;                  // 512
    short* wtA = (short*)(blocksums + 512);              // 24576 shorts
    short* wtB = wtA + 24576;
    short* wtG = wtB + 24576;

    hipMemsetAsync(counts, 0, sizeof(int) * NM, stream);

    // fused weight prep: 9 transposed bf16 matrices, one launch
    WAll wa;
    wa.e[0] = {aW0, wtA,          64,     0};
    wa.e[1] = {aW1, wtA + 4096,   64,  4096};
    wa.e[2] = {aW2, wtA + 8192,  256,  8192};
    wa.e[3] = {bW0, wtB,          64, 24576};
    wa.e[4] = {bW1, wtB + 4096,   64, 28672};
    wa.e[5] = {bW2, wtB + 8192,  256, 32768};
    wa.e[6] = {gW0, wtG,          64, 49152};
    wa.e[7] = {gW1, wtG + 4096,   64, 53248};
    wa.e[8] = {gW2, wtG + 8192,  256, 57344};
    wprep_all_kernel<<<288, 256, 0, stream>>>(wa);

    mlp_mfma_kernel<<<(NM + 63) / 64, 256, 0, stream>>>(
        master, NM, wtA, ab0, wtA + 4096, ab1, wtA + 8192, attn_r, er, nullptr);
    mlp_mfma_kernel<<<(NB + 63) / 64, 256, 0, stream>>>(
        bond, NB, wtB, bb0, wtB + 4096, bb1, wtB + 8192, attn_l, el_b, ft_b);
    mlp_mfma_kernel<<<(NG + 63) / 64, 256, 0, stream>>>(
        glob, NG, wtG, gb0, wtG + 4096, gb1, wtG + 8192, attn_l, el_g, ft_g);

    hist_kernel<<<(NE + 255) / 256, 256, 0, stream>>>(e1_dst, e2_dst, counts);
    scan1_kernel<<<SCAN_BLOCKS, 256, 0, stream>>>(counts, prefix_inc, blocksums);
    scan2_kernel<<<1, 512, 0, stream>>>(blocksums);
    scan3_kernel<<<SCAN_BLOCKS + 1, 256, 0, stream>>>(counts, prefix_inc, blocksums,
                                                      offsets, cursor);
    fill_kernel<<<(NE + 255) / 256, 256, 0, stream>>>(e1_src, e1_dst, e2_src, e2_dst,
                                                      er, el_b, el_g,
                                                      cursor, sorted, vsort);
    aggregate_kernel<<<4096, 256, 0, stream>>>(offsets, sorted, (const float*)vsort,
                                               ft_b, ft_g, out);
}

// Round 5
// 250.410 us; speedup vs baseline: 5.4805x; 1.2825x over previous
//
#include <hip/hip_runtime.h>

#define NM 100000
#define NB 200000
#define NG 5000
#define NE1 400000
#define NE2 100000
#define NE (NE1 + NE2)
#define NMP 100004  // NM+1 rounded up to keep 16B alignment of later ws regions
#define SCAN_BLOCKS 391  // 391*256 = 100096 >= NM

typedef __attribute__((ext_vector_type(8))) short bf16x8;
typedef __attribute__((ext_vector_type(4))) short short4v;
typedef __attribute__((ext_vector_type(4))) float f32x4;

__device__ __forceinline__ unsigned short f2bf(float f) {
    unsigned int u = __float_as_uint(f);
    u += 0x7FFFu + ((u >> 16) & 1u);   // round-to-nearest-even
    return (unsigned short)(u >> 16);
}
__device__ __forceinline__ float bf2f(unsigned short u) {
    return __uint_as_float((unsigned int)u << 16);
}
__device__ __forceinline__ float elu_f(float x) {
    return x > 0.f ? x : __expf(x) - 1.f;
}
// swizzled LDS address: activation tile row j (128B), 16B-slot XOR by (j&7)
__device__ __forceinline__ char* swz(char* base, int j, int byteoff) {
    return base + j * 128 + ((((byteoff >> 4) ^ (j & 7)) << 4) | (byteoff & 15));
}

// ---------------------------------------------------------------------------
// Weight prep (all 9 matrices in one launch): Wt[i][k] = bf16(W[k][i]), K=64.
// ---------------------------------------------------------------------------
struct WEnt { const float* W; short* o; int I; int off; };
struct WAll { WEnt e[9]; };

__global__ __launch_bounds__(256) void wprep_all_kernel(WAll a)
{
    const int idx = blockIdx.x * 256 + threadIdx.x;  // grid sized exactly
    #pragma unroll
    for (int j = 8; j >= 0; --j) {
        if (idx >= a.e[j].off) {
            const int local = idx - a.e[j].off;
            const int I = a.e[j].I;
            const int i = local >> 6, k = local & 63;
            a.e[j].o[local] = (short)f2bf(a.e[j].W[k * I + i]);
            break;
        }
    }
}

// ---------------------------------------------------------------------------
// Fused 3-layer MLP via bf16 MFMA, transposed-product formulation.
// ---------------------------------------------------------------------------
__global__ __launch_bounds__(256) void mlp_mfma_kernel(
    const float* __restrict__ x, int N,
    const short* __restrict__ W0t, const float* __restrict__ b0,
    const short* __restrict__ W1t, const float* __restrict__ b1,
    const short* __restrict__ W2t,
    const float* __restrict__ attn,    // (4,64) f32
    float* __restrict__ score,         // (N,4)
    unsigned short* __restrict__ ft_out) // (N,256) bf16 or nullptr
{
    __shared__ __attribute__((aligned(128))) char ldsA[64 * 128];
    __shared__ __attribute__((aligned(128))) char ldsB[64 * 128];

    const int tid = threadIdx.x;
    const int w = tid >> 6, l = tid & 63;
    const int g = l >> 4, c = l & 15;
    const int r0 = blockIdx.x << 6;

    // ---- stage x tile: f32 -> bf16, swizzled [j][k] ----
    {
        const int j = tid >> 2, q = tid & 3;
        const int row = r0 + j;
        bf16x8 o0 = (bf16x8)0, o1 = (bf16x8)0;
        if (row < N) {
            const float4* xp = (const float4*)(x + ((size_t)row << 6) + (q << 4));
            #pragma unroll
            for (int u = 0; u < 2; ++u) {
                float4 v = xp[u];
                o0[u*4+0] = (short)f2bf(v.x); o0[u*4+1] = (short)f2bf(v.y);
                o0[u*4+2] = (short)f2bf(v.z); o0[u*4+3] = (short)f2bf(v.w);
            }
            #pragma unroll
            for (int u = 0; u < 2; ++u) {
                float4 v = xp[u + 2];
                o1[u*4+0] = (short)f2bf(v.x); o1[u*4+1] = (short)f2bf(v.y);
                o1[u*4+2] = (short)f2bf(v.z); o1[u*4+3] = (short)f2bf(v.w);
            }
        }
        *(bf16x8*)swz(ldsA, j, q * 32)      = o0;
        *(bf16x8*)swz(ldsA, j, q * 32 + 16) = o1;
    }
    __syncthreads();

    // ---- layers 1 and 2 (64->64, ELU) ----
    char* src = ldsA;
    char* dst = ldsB;
    #pragma unroll
    for (int layer = 0; layer < 2; ++layer) {
        const short* Wt = layer ? W1t : W0t;
        const float* bb = layer ? b1 : b0;
        f32x4 acc[4] = {};
        #pragma unroll
        for (int step = 0; step < 2; ++step) {
            bf16x8 a = *(const bf16x8*)(Wt + (((16 * w + c) << 6) + 32 * step + 8 * g));
            #pragma unroll
            for (int t = 0; t < 4; ++t) {
                const int j = 16 * t + c;
                bf16x8 b = *(const bf16x8*)swz(src, j, 64 * step + 16 * g);
                acc[t] = __builtin_amdgcn_mfma_f32_16x16x32_bf16(a, b, acc[t], 0, 0, 0);
            }
        }
        const int i0 = 16 * w + 4 * g;
        const float4 bias = *(const float4*)(bb + i0);
        #pragma unroll
        for (int t = 0; t < 4; ++t) {
            const int j = 16 * t + c;
            short4v o;
            o[0] = (short)f2bf(elu_f(acc[t][0] + bias.x));
            o[1] = (short)f2bf(elu_f(acc[t][1] + bias.y));
            o[2] = (short)f2bf(elu_f(acc[t][2] + bias.z));
            o[3] = (short)f2bf(elu_f(acc[t][3] + bias.w));
            *(short4v*)swz(dst, j, 32 * w + 8 * g) = o;
        }
        __syncthreads();
        char* tmp = src; src = dst; dst = tmp;
    }

    // ---- layer 3 (64->256, identity, no bias) + scores ----
    {
        f32x4 acc[4][4] = {};  // [it][t]
        #pragma unroll
        for (int step = 0; step < 2; ++step) {
            bf16x8 bfr[4];
            #pragma unroll
            for (int t = 0; t < 4; ++t)
                bfr[t] = *(const bf16x8*)swz(src, 16 * t + c, 64 * step + 16 * g);
            #pragma unroll
            for (int it = 0; it < 4; ++it) {
                bf16x8 a = *(const bf16x8*)(W2t + (((64 * w + 16 * it + c) << 6) + 32 * step + 8 * g));
                #pragma unroll
                for (int t = 0; t < 4; ++t)
                    acc[it][t] = __builtin_amdgcn_mfma_f32_16x16x32_bf16(a, bfr[t], acc[it][t], 0, 0, 0);
            }
        }
        float4 av[4];
        #pragma unroll
        for (int it = 0; it < 4; ++it)
            av[it] = *(const float4*)(attn + 64 * w + 16 * it + 4 * g);

        #pragma unroll
        for (int t = 0; t < 4; ++t) {
            const int row = r0 + 16 * t + c;
            float p = 0.f;
            #pragma unroll
            for (int it = 0; it < 4; ++it) {
                p += acc[it][t][0] * av[it].x + acc[it][t][1] * av[it].y
                   + acc[it][t][2] * av[it].z + acc[it][t][3] * av[it].w;
            }
            p += __shfl_xor(p, 16);
            p += __shfl_xor(p, 32);
            if (row < N) {
                if (g == 0) score[(row << 2) + w] = p;
                if (ft_out) {
                    #pragma unroll
                    for (int it = 0; it < 4; ++it) {
                        short4v o;
                        o[0] = (short)f2bf(acc[it][t][0]);
                        o[1] = (short)f2bf(acc[it][t][1]);
                        o[2] = (short)f2bf(acc[it][t][2]);
                        o[3] = (short)f2bf(acc[it][t][3]);
                        *(short4v*)(ft_out + ((size_t)row << 8) + 64 * w + 16 * it + 4 * g) = o;
                    }
                }
            }
        }
    }
}

// ---------------------------------------------------------------------------
// CSR build: histogram -> 3-phase parallel scan -> fill (+ per-edge logits)
// ---------------------------------------------------------------------------
__global__ void hist_kernel(const int* __restrict__ e1_dst,
                            const int* __restrict__ e2_dst,
                            int* __restrict__ counts)
{
    int i = blockIdx.x * blockDim.x + threadIdx.x;
    if (i < NE1) atomicAdd(&counts[e1_dst[i]], 1);
    else if (i < NE) atomicAdd(&counts[e2_dst[i - NE1]], 1);
}

// phase 1: per-block inclusive prefix + block totals
__global__ __launch_bounds__(256) void scan1_kernel(
    const int* __restrict__ counts,
    int* __restrict__ prefix_inc,
    int* __restrict__ blocksums)
{
    const int i = blockIdx.x * 256 + threadIdx.x;
    const int lane = threadIdx.x & 63, wv = threadIdx.x >> 6;
    int v = (i < NM) ? counts[i] : 0;
    int x = v;
    #pragma unroll
    for (int o = 1; o < 64; o <<= 1) {
        int u = __shfl_up(x, o);
        if (lane >= o) x += u;
    }
    __shared__ int wsum[4];
    if (lane == 63) wsum[wv] = x;
    __syncthreads();
    int add = 0;
    #pragma unroll
    for (int k = 0; k < 3; ++k) add += (k < wv) ? wsum[k] : 0;
    x += add;
    if (i < NM) prefix_inc[i] = x;
    if (threadIdx.x == 255) blocksums[blockIdx.x] = x;
}

// phase 2: exclusive scan of the 391 block totals (one block)
__global__ __launch_bounds__(512) void scan2_kernel(int* __restrict__ blocksums)
{
    const int t = threadIdx.x;
    const int lane = t & 63, wv = t >> 6;
    int v = (t < SCAN_BLOCKS) ? blocksums[t] : 0;
    int x = v;
    #pragma unroll
    for (int o = 1; o < 64; o <<= 1) {
        int u = __shfl_up(x, o);
        if (lane >= o) x += u;
    }
    __shared__ int wsum[8];
    if (lane == 63) wsum[wv] = x;
    __syncthreads();
    int add = 0;
    #pragma unroll
    for (int k = 0; k < 7; ++k) add += (k < wv) ? wsum[k] : 0;
    x += add;
    if (t < SCAN_BLOCKS) blocksums[t] = x - v;  // exclusive
}

// phase 3: offsets[i] = inclusive[i] - counts[i] + blockbase; init cursor
__global__ __launch_bounds__(256) void scan3_kernel(
    const int* __restrict__ counts,
    const int* __restrict__ prefix_inc,
    const int* __restrict__ blocksums,
    int* __restrict__ offsets,
    int* __restrict__ cursor)
{
    const int i = blockIdx.x * 256 + threadIdx.x;
    if (i > NM) return;
    if (i == NM) { offsets[NM] = NE; return; }
    const int off = prefix_inc[i] - counts[i] + blocksums[blockIdx.x];
    offsets[i] = off;
    cursor[i]  = off;
}

// fill: place edge into CSR slot AND compute v = leaky(el[src] + er[dst])
__global__ void fill_kernel(const int* __restrict__ e1_src,
                            const int* __restrict__ e1_dst,
                            const int* __restrict__ e2_src,
                            const int* __restrict__ e2_dst,
                            const float* __restrict__ er,
                            const float* __restrict__ el_b,
                            const float* __restrict__ el_g,
                            int* __restrict__ cursor,
                            int* __restrict__ sorted,
                            float4* __restrict__ vsort)
{
    int i = blockIdx.x * blockDim.x + threadIdx.x;
    if (i >= NE) return;
    int dst, src, enc;
    const float* el;
    if (i < NE1) { src = e1_src[i]; dst = e1_dst[i]; enc = src;              el = el_b; }
    else { int j = i - NE1; src = e2_src[j]; dst = e2_dst[j]; enc = src | (1 << 30); el = el_g; }
    const float4 l4 = *(const float4*)(el + (src << 2));
    const float4 r4 = *(const float4*)(er + (dst << 2));
    float4 v;
    v.x = l4.x + r4.x; v.x = v.x > 0.f ? v.x : 0.2f * v.x;
    v.y = l4.y + r4.y; v.y = v.y > 0.f ? v.y : 0.2f * v.y;
    v.z = l4.z + r4.z; v.z = v.z > 0.f ? v.z : 0.2f * v.z;
    v.w = l4.w + r4.w; v.w = v.w > 0.f ? v.w : 0.2f * v.w;
    int p = atomicAdd(&cursor[dst], 1);
    sorted[p] = enc;
    vsort[p] = v;
}

// ---------------------------------------------------------------------------
// Aggregation: ONE WAVE per node, 4 independent nodes per 256-thr block.
// Lane l owns features [4l,4l+4); head h = l>>4. Per-head max/sum are scalar
// per-lane serial loops over the contiguous segment (L1 broadcast loads) —
// zero shuffles, zero __syncthreads. Two passes: max, then exp+accumulate;
// final 1/s scale.
// ---------------------------------------------------------------------------
__global__ __launch_bounds__(256) void aggregate_kernel(
    const int* __restrict__ offsets,
    const int* __restrict__ sorted,
    const float* __restrict__ vsort,        // (NE,4)
    const unsigned short* __restrict__ ftb, // (NB,256) bf16
    const unsigned short* __restrict__ ftg, // (NG,256) bf16
    float* __restrict__ out)                // (NM,256)
{
    const int w = threadIdx.x >> 6, l = threadIdx.x & 63;
    const int h  = l >> 4;       // head for this lane
    const int f4 = l << 2;       // feature base

    const int n = (blockIdx.x << 2) + w;
    if (n >= NM) return;

    const int start = offsets[n];
    const int deg   = offsets[n + 1] - start;

    float ax = 0.f, ay = 0.f, az = 0.f, aw = 0.f;
    if (deg > 0) {
        float m = -1e30f;
        for (int e = 0; e < deg; ++e)
            m = fmaxf(m, vsort[((start + e) << 2) + h]);

        float s = 0.f;
        for (int e = 0; e < deg; ++e) {
            const float wgt = __expf(vsort[((start + e) << 2) + h] - m);
            s += wgt;
            const int enc = sorted[start + e];
            const int isg = enc >> 30;
            const int src = enc & 0x3FFFFFFF;
            const unsigned short* ft =
                (isg ? ftg : ftb) + ((size_t)src << 8) + f4;
            const short4v u = *(const short4v*)ft;
            ax = fmaf(bf2f((unsigned short)u[0]), wgt, ax);
            ay = fmaf(bf2f((unsigned short)u[1]), wgt, ay);
            az = fmaf(bf2f((unsigned short)u[2]), wgt, az);
            aw = fmaf(bf2f((unsigned short)u[3]), wgt, aw);
        }
        const float inv = 1.f / s;
        ax *= inv; ay *= inv; az *= inv; aw *= inv;
    }
    float4 o = make_float4(ax, ay, az, aw);
    *(float4*)(out + ((size_t)n << 8) + f4) = o;
}

// ---------------------------------------------------------------------------
extern "C" void kernel_launch(void* const* d_in, const int* in_sizes, int n_in,
                              void* d_out, int out_size, void* d_ws, size_t ws_size,
                              hipStream_t stream)
{
    const float* master = (const float*)d_in[0];
    const float* bond   = (const float*)d_in[1];
    const float* glob   = (const float*)d_in[2];
    const float* aW0 = (const float*)d_in[3];
    const float* ab0 = (const float*)d_in[4];
    const float* aW1 = (const float*)d_in[5];
    const float* ab1 = (const float*)d_in[6];
    const float* aW2 = (const float*)d_in[7];
    const float* bW0 = (const float*)d_in[8];
    const float* bb0 = (const float*)d_in[9];
    const float* bW1 = (const float*)d_in[10];
    const float* bb1 = (const float*)d_in[11];
    const float* bW2 = (const float*)d_in[12];
    const float* gW0 = (const float*)d_in[13];
    const float* gb0 = (const float*)d_in[14];
    const float* gW1 = (const float*)d_in[15];
    const float* gb1 = (const float*)d_in[16];
    const float* gW2 = (const float*)d_in[17];
    const float* attn_l = (const float*)d_in[18];
    const float* attn_r = (const float*)d_in[19];
    const int* e1_src = (const int*)d_in[20];
    const int* e1_dst = (const int*)d_in[21];
    const int* e2_src = (const int*)d_in[22];
    const int* e2_dst = (const int*)d_in[23];
    float* out = (float*)d_out;

    // workspace layout
    float* ws   = (float*)d_ws;
    unsigned short* ft_b = (unsigned short*)ws;          // NB*256 bf16
    unsigned short* ft_g = ft_b + (size_t)NB * 256;      // NG*256 bf16
    float* er   = (float*)(ft_g + (size_t)NG * 256);     // NM*4
    float* el_b = er + (size_t)NM * 4;                   // NB*4
    float* el_g = el_b + (size_t)NB * 4;                 // NG*4
    int* counts  = (int*)(el_g + (size_t)NG * 4);        // NMP
    int* offsets = counts + NMP;                         // NMP
    int* cursor  = offsets + NMP;                        // NMP
    int* sorted  = cursor + NMP;                         // NE
    float4* vsort = (float4*)(sorted + NE);              // NE float4
    int* prefix_inc = (int*)(vsort + NE);                // NMP
    int* blocksums  = prefix_inc + NMP;                  // 512
    short* wtA = (short*)(blocksums + 512);              // 24576 shorts
    short* wtB = wtA + 24576;
    short* wtG = wtB + 24576;

    hipMemsetAsync(counts, 0, sizeof(int) * NM, stream);

    // fused weight prep: 9 transposed bf16 matrices, one launch
    WAll wa;
    wa.e[0] = {aW0, wtA,          64,     0};
    wa.e[1] = {aW1, wtA + 4096,   64,  4096};
    wa.e[2] = {aW2, wtA + 8192,  256,  8192};
    wa.e[3] = {bW0, wtB,          64, 24576};
    wa.e[4] = {bW1, wtB + 4096,   64, 28672};
    wa.e[5] = {bW2, wtB + 8192,  256, 32768};
    wa.e[6] = {gW0, wtG,          64, 49152};
    wa.e[7] = {gW1, wtG + 4096,   64, 53248};
    wa.e[8] = {gW2, wtG + 8192,  256, 57344};
    wprep_all_kernel<<<288, 256, 0, stream>>>(wa);

    mlp_mfma_kernel<<<(NM + 63) / 64, 256, 0, stream>>>(
        master, NM, wtA, ab0, wtA + 4096, ab1, wtA + 8192, attn_r, er, nullptr);
    mlp_mfma_kernel<<<(NB + 63) / 64, 256, 0, stream>>>(
        bond, NB, wtB, bb0, wtB + 4096, bb1, wtB + 8192, attn_l, el_b, ft_b);
    mlp_mfma_kernel<<<(NG + 63) / 64, 256, 0, stream>>>(
        glob, NG, wtG, gb0, wtG + 4096, gb1, wtG + 8192, attn_l, el_g, ft_g);

    hist_kernel<<<(NE + 255) / 256, 256, 0, stream>>>(e1_dst, e2_dst, counts);
    scan1_kernel<<<SCAN_BLOCKS, 256, 0, stream>>>(counts, prefix_inc, blocksums);
    scan2_kernel<<<1, 512, 0, stream>>>(blocksums);
    scan3_kernel<<<SCAN_BLOCKS + 1, 256, 0, stream>>>(counts, prefix_inc, blocksums,
                                                      offsets, cursor);
    fill_kernel<<<(NE + 255) / 256, 256, 0, stream>>>(e1_src, e1_dst, e2_src, e2_dst,
                                                      er, el_b, el_g,
                                                      cursor, sorted, vsort);
    aggregate_kernel<<<(NM + 3) / 4, 256, 0, stream>>>(offsets, sorted,
                                                       (const float*)vsort,
                                                       ft_b, ft_g, out);
}